// Round 22
// baseline (209.505 us; speedup 1.0000x reference)
//
#include <hip/hip_runtime.h>
#include <hip/hip_fp16.h>

#define HD 128
#define BSH 9              // 512 dst-nodes per bucket
#define NBLKA 256          // phase-A persistent blocks
#define CAP 96             // per (block,bucket) cell capacity (mean ~32, +11 sigma)
#define EDSCAP 10240       // LDS edge stage per bucket (mean ~8.2K)
#define CAPB 12288         // fixed col-region capacity per bucket
// xs tile: 16 rows x 128 halfs, 16B-unit XOR swizzle (col8 ^ row&7)
#define XSW(row, c8) (((size_t)(row) << 7) + ((size_t)(((c8) ^ ((row) & 7))) << 3))

typedef _Float16 half8_t __attribute__((ext_vector_type(8)));
typedef float floatx4 __attribute__((ext_vector_type(4)));

__device__ inline unsigned pack_h2(float x, float y) {
  __half2 h = __floats2half2_rn(x, y);
  return __builtin_bit_cast(unsigned, h);
}
__device__ inline float2 up_h2(unsigned u) {
  __half2 h = __builtin_bit_cast(__half2, u);
  return __half22float2(h);
}

__device__ inline void add8(float* acc, uint4 r) {
  float2 f;
  f = up_h2(r.x); acc[0] += f.x; acc[1] += f.y;
  f = up_h2(r.y); acc[2] += f.x; acc[3] += f.y;
  f = up_h2(r.z); acc[4] += f.x; acc[5] += f.y;
  f = up_h2(r.w); acc[6] += f.x; acc[7] += f.y;
}

__device__ inline void fma8w(float* acc, uint4 r, float w) {
  float2 f;
  f = up_h2(r.x); acc[0] = fmaf(w, f.x, acc[0]); acc[1] = fmaf(w, f.y, acc[1]);
  f = up_h2(r.y); acc[2] = fmaf(w, f.x, acc[2]); acc[3] = fmaf(w, f.y, acc[3]);
  f = up_h2(r.z); acc[4] = fmaf(w, f.x, acc[4]); acc[5] = fmaf(w, f.y, acc[5]);
  f = up_h2(r.w); acc[6] = fmaf(w, f.x, acc[6]); acc[7] = fmaf(w, f.y, acc[7]);
}

// ---- phase 0 (merged): bucketA | W frag pre-pack | ci + flag/dhist/dcur zero ----
__global__ __launch_bounds__(256) void k_phase0(const int* __restrict__ src,
                                                const int* __restrict__ dst, int E, int nbuck,
                                                unsigned* __restrict__ bpool,
                                                int* __restrict__ counts,
                                                const float* __restrict__ conv_w,
                                                uint4* __restrict__ wfrag,
                                                const int* __restrict__ batch,
                                                int* __restrict__ ci,
                                                int* __restrict__ flag,
                                                int* __restrict__ dhist,
                                                int* __restrict__ dcur,
                                                int n) {
  __shared__ int cnt[512];
  int b = blockIdx.x;
  if (b < NBLKA) {  // ---- bucketA ----
    for (int i = threadIdx.x; i < nbuck; i += 256) cnt[i] = 0;
    __syncthreads();
    int chunk = (E + NBLKA - 1) / NBLKA;
    int lo = b * chunk, hi = min(E, lo + chunk);
    for (int i = lo + threadIdx.x; i < hi; i += 256) {
      int s = src[i], d = dst[i];
      int bk = d >> BSH;
      int c = atomicAdd(&cnt[bk], 1);
      if (c < CAP)
        bpool[((size_t)bk * NBLKA + b) * CAP + c] =
            ((unsigned)(d & ((1 << BSH) - 1)) << 23) | (unsigned)s;
    }
    __syncthreads();
    for (int bk = threadIdx.x; bk < nbuck; bk += 256) counts[(size_t)bk * NBLKA + b] = cnt[bk];
  } else if (b < NBLKA + 24) {  // ---- wprep ----
    int t = (b - NBLKA) * 256 + threadIdx.x;
    int lane = t & 63;
    int s = (t >> 6) & 3;
    int c4 = (t >> 8) & 3;
    int chalf = (t >> 10) & 1;
    int layer = t >> 11;
    int col = chalf * 64 + c4 * 16 + (lane & 15);
    int k0 = s * 32 + (lane >> 4) * 8;
    const float* W = conv_w + (size_t)layer * HD * HD;
    unsigned u[4];
#pragma unroll
    for (int j = 0; j < 4; ++j)
      u[j] = pack_h2(W[(size_t)(k0 + 2 * j) * HD + col], W[(size_t)(k0 + 2 * j + 1) * HD + col]);
    uint4 o; o.x = u[0]; o.y = u[1]; o.z = u[2]; o.w = u[3];
    wfrag[t] = o;
  } else {  // ---- ci + zeroing ----
    int i = (b - NBLKA - 24) * 256 + threadIdx.x;
    if (i >= n) return;
    flag[i] = 0;
    if (i == 0) flag[n] = 0;  // active counter
    if (i < 64) { dhist[i] = 0; dcur[i] = 0; }
    if (i == 0 || batch[i] != batch[i - 1]) ci[batch[i]] = i;
  }
}

// ---- gemm phase: 16 swizzled LDS rows x W -> output rows (dinv nullable) ----
__device__ inline void gemm16(const _Float16* xs, const uint4* __restrict__ wfragL,
                              const float* __restrict__ dinv, uint2* __restrict__ Yh,
                              int row0, int nvalid, const int* __restrict__ rowmap,
                              int tid) {
  int lane = tid & 63, w = tid >> 6;
  int chalf = w >> 1, h = lane >> 4;
  half8_t wf[8];
#pragma unroll
  for (int cc = 0; cc < 2; ++cc)
#pragma unroll
    for (int s = 0; s < 4; ++s) {
      int c4 = 2 * (w & 1) + cc;
      wf[cc * 4 + s] = __builtin_bit_cast(half8_t,
          wfragL[((chalf * 4 + c4) * 4 + s) * 64 + lane]);
    }
  half8_t bf[4];
#pragma unroll
  for (int s = 0; s < 4; ++s)
    bf[s] = *(const half8_t*)&xs[XSW(lane & 15, s * 4 + h)];
  floatx4 acc[2];
  acc[0] = (floatx4){0.f, 0.f, 0.f, 0.f};
  acc[1] = (floatx4){0.f, 0.f, 0.f, 0.f};
#pragma unroll
  for (int s = 0; s < 4; ++s) {
    acc[0] = __builtin_amdgcn_mfma_f32_16x16x32_f16(wf[s], bf[s], acc[0], 0, 0, 0);
    acc[1] = __builtin_amdgcn_mfma_f32_16x16x32_f16(wf[4 + s], bf[s], acc[1], 0, 0, 0);
  }
  int i = row0 + (lane & 15);
  if (i < nvalid) {
    int orow = rowmap ? rowmap[i] : i;
    float dv = dinv ? dinv[orow] : 1.0f;
#pragma unroll
    for (int cc = 0; cc < 2; ++cc) {
      int c4 = 2 * (w & 1) + cc;
      int colbase = chalf * 64 + c4 * 16 + h * 4;
      uint2 o;
      o.x = pack_h2(acc[cc][0] * dv, acc[cc][1] * dv);
      o.y = pack_h2(acc[cc][2] * dv, acc[cc][3] * dv);
      Yh[(size_t)orow * 32 + (colbase >> 2)] = o;
    }
  }
}

// ---- build: CSR per bucket (+D2, degree hist) | T0 = emb_table @ W0 (extra blocks) ----
__global__ __launch_bounds__(256) void k_build(const unsigned* __restrict__ bpool,
                                               const int* __restrict__ counts,
                                               int n, int nbuck, int maxz,
                                               const int* __restrict__ z,
                                               const float4* __restrict__ emb,
                                               const uint4* __restrict__ wfrag0,
                                               float* __restrict__ dinv,
                                               uint2* __restrict__ d2,
                                               uint2* __restrict__ t0,
                                               int* __restrict__ rowstart,
                                               int* __restrict__ rowend,
                                               int* __restrict__ col,
                                               int* __restrict__ dhist) {
  __shared__ __align__(16) unsigned eds[EDSCAP];
  __shared__ int hist[1 << BSH];
  __shared__ int wsum[256];
  __shared__ int coff[NBLKA + 1];
  __shared__ int h64[64];
  int b = blockIdx.x;
  int t = threadIdx.x;
  if (b >= nbuck) {  // ---- T0 block: rows [rb*16, rb*16+16) of emb_table @ W0 ----
    int rb = b - nbuck;
    _Float16* xs = (_Float16*)eds;
    int grp = t >> 4, li = t & 15;
    int row = rb * 16 + grp;
    int r = row < maxz ? row : maxz - 1;
    const float4* er = emb + (size_t)r * 32 + li * 2;
    float4 f0 = er[0], f1 = er[1];
    uint4 hx;
    hx.x = pack_h2(f0.x, f0.y); hx.y = pack_h2(f0.z, f0.w);
    hx.z = pack_h2(f1.x, f1.y); hx.w = pack_h2(f1.z, f1.w);
    *(uint4*)&xs[XSW(grp, li)] = hx;
    __syncthreads();
    gemm16(xs, wfrag0, nullptr, t0, rb * 16, maxz, nullptr, t);
    return;
  }
  int v = (t < NBLKA) ? min(counts[(size_t)b * NBLKA + t], CAP) : 0;
  wsum[t] = v;
  if (t < 64) h64[t] = 0;
  __syncthreads();
  for (int off = 1; off < NBLKA; off <<= 1) {
    int x = (t >= off) ? wsum[t - off] : 0;
    __syncthreads();
    wsum[t] += x;
    __syncthreads();
  }
  if (t < NBLKA) coff[t] = wsum[t] - v;
  if (t == NBLKA - 1) coff[NBLKA] = wsum[NBLKA - 1];
  __syncthreads();
  int total = min(coff[NBLKA], EDSCAP);
  int w = t >> 6, lane = t & 63;
  for (int blk = w; blk < NBLKA; blk += 4) {
    int off0 = coff[blk], len = coff[blk + 1] - off0;
    const unsigned* seg = bpool + ((size_t)b * NBLKA + blk) * CAP;
    for (int i = lane; i < len; i += 64)
      if (off0 + i < EDSCAP) eds[off0 + i] = seg[i];
  }
  for (int i = t; i < (1 << BSH); i += 256) hist[i] = 0;
  __syncthreads();
  for (int i = t; i < total; i += 256) atomicAdd(&hist[eds[i] >> 23], 1);
  __syncthreads();
  int base = b << BSH;
  int nn = min(1 << BSH, n - base);
  int a0 = hist[2 * t], a1 = hist[2 * t + 1];
  int s = a0 + a1;
  wsum[t] = s;
  __syncthreads();
  for (int off = 1; off < 256; off <<= 1) {
    int x = (t >= off) ? wsum[t - off] : 0;
    __syncthreads();
    wsum[t] += x;
    __syncthreads();
  }
  int excl = wsum[t] - s;
  int cbase = b * CAPB;
  if (2 * t < nn) {
    int i = base + 2 * t;
    float d = 1.0f / sqrtf((float)(a0 + 1));
    rowstart[i] = cbase + excl;
    rowend[i] = cbase + excl + a0;
    dinv[i] = d;
    d2[i] = make_uint2((unsigned)z[i] * 16, __float_as_uint(d));
    atomicAdd(&h64[min(a0, 63)], 1);
  }
  if (2 * t + 1 < nn) {
    int i = base + 2 * t + 1;
    float d = 1.0f / sqrtf((float)(a1 + 1));
    rowstart[i] = cbase + excl + a0;
    rowend[i] = cbase + excl + s;
    dinv[i] = d;
    d2[i] = make_uint2((unsigned)z[i] * 16, __float_as_uint(d));
    atomicAdd(&h64[min(a1, 63)], 1);
  }
  hist[2 * t] = cbase + excl;
  hist[2 * t + 1] = cbase + excl + a0;
  __syncthreads();
  if (t < 64 && h64[t]) atomicAdd(&dhist[t], h64[t]);
  for (int i = t; i < total; i += 256) {
    unsigned pk = eds[i];
    int dl = pk >> 23;
    int pos = atomicAdd(&hist[dl], 1);
    col[pos] = (int)(pk & 0x7FFFFF);
  }
}

// ---- order (degree counting-sort scatter) | active set (wave-ballot), one kernel ----
__global__ __launch_bounds__(256) void k_order(const int* __restrict__ rowstart,
                                               const int* __restrict__ rowend,
                                               const int* __restrict__ col,
                                               const int* __restrict__ dhist,
                                               int* __restrict__ dcur,
                                               int* __restrict__ order,
                                               const int* __restrict__ ci,
                                               int g2, int* __restrict__ flag,
                                               int* __restrict__ list, int n, int nob) {
  int b = blockIdx.x;
  int t = threadIdx.x;
  if (b < nob) {  // ---- degree-sort scatter ----
    __shared__ int bassh[64];
    __shared__ int lcnt[64], lbase[64];
    if (t == 0) {
      int s = 0;
      for (int j = 0; j < 64; ++j) { bassh[j] = s; s += dhist[j]; }
    }
    if (t < 64) lcnt[t] = 0;
    __syncthreads();
    int i = b * 256 + t;
    int bin = 0, r = 0;
    bool valid = i < n;
    if (valid) {
      bin = min(rowend[i] - rowstart[i], 63);
      r = atomicAdd(&lcnt[bin], 1);
    }
    __syncthreads();
    if (t < 64) lbase[t] = lcnt[t] ? atomicAdd(&dcur[t], lcnt[t]) : 0;
    __syncthreads();
    if (valid) order[bassh[bin] + lbase[bin] + r] = i;
  } else {  // ---- active set ----
    int lane = t & 63;
    int vid = (b - nob) * 256 + t;
    bool haveRow = vid < g2;
    int* nactive = flag + n;
    int node = 0, e = 0, end = 0;
    if (haveRow) {
      node = ci[vid >> 1] + (vid & 1);
      e = rowstart[node];
      end = rowend[node];
    }
    bool neu = haveRow && (atomicExch(&flag[node], 1) == 0);
    unsigned long long m = __ballot(neu);
    int base = 0;
    if (lane == 0 && m) base = atomicAdd(nactive, __popcll(m));
    base = __shfl(base, 0);
    if (neu) list[base + __popcll(m & ((1ULL << lane) - 1))] = node;
    for (;;) {
      bool act = haveRow && (e < end);
      if (!__any(act)) break;
      int s = act ? col[e] : 0;
      bool nw = act && (atomicExch(&flag[s], 1) == 0);
      unsigned long long mm = __ballot(nw);
      int b2 = 0;
      if (lane == 0 && mm) b2 = atomicAdd(nactive, __popcll(mm));
      b2 = __shfl(b2, 0);
      if (nw) list[b2 + __popcll(mm & ((1ULL << lane) - 1))] = s;
      ++e;
    }
  }
}

// ---- layer0 fused: degree-ordered tiles, T0/D2 aggregation + gemm(W1) -> H'1 ----
__global__ __launch_bounds__(256) void k_agg0_gemm(const uint4* __restrict__ T0,
                                                   const uint2* __restrict__ D2,
                                                   const int* __restrict__ rowstart,
                                                   const int* __restrict__ rowend,
                                                   const int* __restrict__ col,
                                                   const float* __restrict__ dinv,
                                                   const float* __restrict__ bias,
                                                   const uint4* __restrict__ wfragL,
                                                   const int* __restrict__ order,
                                                   uint2* __restrict__ Yh, int n) {
  __shared__ __align__(16) _Float16 xs[16 * HD];
  int tid = threadIdx.x;
  int grp = tid >> 4, li = tid & 15;
  int i16 = blockIdx.x * 16 + grp;
  int nd = order[i16 < n ? i16 : n - 1];
  float acc[8] = {0.f, 0.f, 0.f, 0.f, 0.f, 0.f, 0.f, 0.f};
  uint2 ds = D2[nd];
  fma8w(acc, T0[ds.x + li], __uint_as_float(ds.y));  // self term
  int e = rowstart[nd], end = rowend[nd];
  for (; e + 3 < end; e += 4) {
    int c0 = col[e], c1 = col[e + 1], c2 = col[e + 2], c3 = col[e + 3];
    uint2 p0 = D2[c0], p1 = D2[c1], p2 = D2[c2], p3 = D2[c3];
    uint4 r0 = T0[p0.x + li];
    uint4 r1 = T0[p1.x + li];
    uint4 r2 = T0[p2.x + li];
    uint4 r3 = T0[p3.x + li];
    fma8w(acc, r0, __uint_as_float(p0.y));
    fma8w(acc, r1, __uint_as_float(p1.y));
    fma8w(acc, r2, __uint_as_float(p2.y));
    fma8w(acc, r3, __uint_as_float(p3.y));
  }
  for (; e < end; ++e) {
    uint2 p = D2[col[e]];
    fma8w(acc, T0[p.x + li], __uint_as_float(p.y));
  }
  float dv = dinv[nd];
  float4 b0 = ((const float4*)bias)[2 * li];
  float4 b1 = ((const float4*)bias)[2 * li + 1];
  acc[0] = fmaxf(fmaf(dv, acc[0], b0.x), 0.f);
  acc[1] = fmaxf(fmaf(dv, acc[1], b0.y), 0.f);
  acc[2] = fmaxf(fmaf(dv, acc[2], b0.z), 0.f);
  acc[3] = fmaxf(fmaf(dv, acc[3], b0.w), 0.f);
  acc[4] = fmaxf(fmaf(dv, acc[4], b1.x), 0.f);
  acc[5] = fmaxf(fmaf(dv, acc[5], b1.y), 0.f);
  acc[6] = fmaxf(fmaf(dv, acc[6], b1.z), 0.f);
  acc[7] = fmaxf(fmaf(dv, acc[7], b1.w), 0.f);
  uint4 hx;
  hx.x = pack_h2(acc[0], acc[1]); hx.y = pack_h2(acc[2], acc[3]);
  hx.z = pack_h2(acc[4], acc[5]); hx.w = pack_h2(acc[6], acc[7]);
  *(uint4*)&xs[XSW(grp, li)] = hx;
  __syncthreads();
  gemm16(xs, wfragL, dinv, Yh, blockIdx.x * 16, n, order, tid);
}

// ---- fused aggregate + gemm over the active list (grid-stride tiles of 16) ----
__global__ __launch_bounds__(256) void k_agg_gemmL(const uint4* __restrict__ H,
                                                   const int* __restrict__ rowstart,
                                                   const int* __restrict__ rowend,
                                                   const int* __restrict__ col,
                                                   const float* __restrict__ dinv,
                                                   const float* __restrict__ bias,
                                                   const uint4* __restrict__ wfragL,
                                                   uint2* __restrict__ Yh,
                                                   const int* __restrict__ list,
                                                   const int* __restrict__ nactive) {
  __shared__ __align__(16) _Float16 xs[16 * HD];
  int na = *nactive;
  int tid = threadIdx.x;
  int grp = tid >> 4, li = tid & 15;
  for (int tile = blockIdx.x; tile * 16 < na; tile += gridDim.x) {
    int i = tile * 16 + grp;
    int node = list[i < na ? i : na - 1];
    uint4 srow = H[(size_t)node * 16 + li];
    float acc[8] = {0.f, 0.f, 0.f, 0.f, 0.f, 0.f, 0.f, 0.f};
    add8(acc, srow);
    int e = rowstart[node], end = rowend[node];
    for (; e + 3 < end; e += 4) {
      int c0 = col[e], c1 = col[e + 1], c2 = col[e + 2], c3 = col[e + 3];
      uint4 r0 = H[(size_t)c0 * 16 + li];
      uint4 r1 = H[(size_t)c1 * 16 + li];
      uint4 r2 = H[(size_t)c2 * 16 + li];
      uint4 r3 = H[(size_t)c3 * 16 + li];
      add8(acc, r0);
      add8(acc, r1);
      add8(acc, r2);
      add8(acc, r3);
    }
    for (; e < end; ++e) {
      uint4 r = H[(size_t)col[e] * 16 + li];
      add8(acc, r);
    }
    float dv = dinv[node];
    float4 b0 = ((const float4*)bias)[2 * li];
    float4 b1 = ((const float4*)bias)[2 * li + 1];
    acc[0] = fmaxf(fmaf(dv, acc[0], b0.x), 0.f);
    acc[1] = fmaxf(fmaf(dv, acc[1], b0.y), 0.f);
    acc[2] = fmaxf(fmaf(dv, acc[2], b0.z), 0.f);
    acc[3] = fmaxf(fmaf(dv, acc[3], b0.w), 0.f);
    acc[4] = fmaxf(fmaf(dv, acc[4], b1.x), 0.f);
    acc[5] = fmaxf(fmaf(dv, acc[5], b1.y), 0.f);
    acc[6] = fmaxf(fmaf(dv, acc[6], b1.z), 0.f);
    acc[7] = fmaxf(fmaf(dv, acc[7], b1.w), 0.f);
    uint4 hx;
    hx.x = pack_h2(acc[0], acc[1]); hx.y = pack_h2(acc[2], acc[3]);
    hx.z = pack_h2(acc[4], acc[5]); hx.w = pack_h2(acc[6], acc[7]);
    *(uint4*)&xs[XSW(grp, li)] = hx;
    __syncthreads();
    gemm16(xs, wfragL, dinv, Yh, tile * 16, na, list, tid);
    __syncthreads();
  }
}

// ---- fused tail: final aggregate of both center rows + product + MLP head ----
__global__ __launch_bounds__(128) void k_tail(const uint4* __restrict__ H,
                                              const int* __restrict__ rowstart,
                                              const int* __restrict__ rowend,
                                              const int* __restrict__ col,
                                              const float* __restrict__ dinv,
                                              const float* __restrict__ bias,
                                              const int* __restrict__ ci,
                                              const float* __restrict__ W1,
                                              const float* __restrict__ b1,
                                              const float* __restrict__ w2,
                                              const float* __restrict__ b2,
                                              float* __restrict__ out, int G) {
  __shared__ float part[8][HD];
  __shared__ float xs[HD];
  __shared__ float red[HD];
  int g = blockIdx.x;
  int t = threadIdx.x;
  int grp = t >> 4, li = t & 15;
  int nodeA = ci[g];
  int node = nodeA + (grp >> 2);   // 0-3 -> A, 4-7 -> B
  int gi = grp & 3;
  float acc[8] = {0.f, 0.f, 0.f, 0.f, 0.f, 0.f, 0.f, 0.f};
  if (gi == 0) add8(acc, H[(size_t)node * 16 + li]);  // self term
  for (int e = rowstart[node] + gi; e < rowend[node]; e += 4) {
    uint4 r = H[(size_t)col[e] * 16 + li];
    add8(acc, r);
  }
#pragma unroll
  for (int j = 0; j < 8; ++j) part[grp][li * 8 + j] = acc[j];
  __syncthreads();
  float sumA = part[0][t] + part[1][t] + part[2][t] + part[3][t];
  float sumB = part[4][t] + part[5][t] + part[6][t] + part[7][t];
  float bb = bias[t];
  float va = fmaf(dinv[nodeA], sumA, bb);
  float vb = fmaf(dinv[nodeA + 1], sumB, bb);
  xs[t] = va * vb;
  __syncthreads();
  float hacc = b1[t];
#pragma unroll 8
  for (int k = 0; k < HD; ++k) hacc = fmaf(xs[k], W1[k * HD + t], hacc);
  hacc = fmaxf(hacc, 0.f);
  red[t] = hacc * w2[t];
  __syncthreads();
  for (int off = 64; off > 0; off >>= 1) {
    if (t < off) red[t] += red[t + off];
    __syncthreads();
  }
  if (t == 0) out[g] = red[0] + b2[0];
}

extern "C" void kernel_launch(void* const* d_in, const int* in_sizes, int n_in,
                              void* d_out, int out_size, void* d_ws, size_t ws_size,
                              hipStream_t stream) {
  (void)n_in; (void)ws_size;
  const int*   z      = (const int*)d_in[1];
  const int*   ei     = (const int*)d_in[2];
  const int*   batch  = (const int*)d_in[3];
  const float* emb    = (const float*)d_in[4];
  const float* conv_w = (const float*)d_in[5];
  const float* conv_b = (const float*)d_in[6];
  const float* w1     = (const float*)d_in[7];
  const float* b1     = (const float*)d_in[8];
  const float* w2     = (const float*)d_in[9];
  const float* b2     = (const float*)d_in[10];
  int n = in_sizes[1];
  int E = in_sizes[2] / 2;
  int G = out_size;
  int maxz = in_sizes[4] / HD;
  const int* esrc = ei;
  const int* edst = ei + E;
  int nbuck = (n + (1 << BSH) - 1) >> BSH;
  int t0Blocks = (maxz + 15) / 16;

  char* p = (char*)d_ws;
  auto alloc = [&](size_t bytes) { void* r = (void*)p; p += (bytes + 255) / 256 * 256; return r; };
  unsigned* bufA     = (unsigned*)alloc((size_t)n * HD * 2);  // half, row-major
  unsigned* bufB     = (unsigned*)alloc((size_t)n * HD * 2);  // half, row-major
  float*    dinv     = (float*)alloc((size_t)n * 4);
  uint2*    d2       = (uint2*)alloc((size_t)n * 8);
  uint2*    t0       = (uint2*)alloc((size_t)(t0Blocks * 16) * 32 * 8);  // fp16 rows
  int*      rowstart = (int*)alloc((size_t)n * 4);
  int*      rowend   = (int*)alloc((size_t)n * 4);
  int*      col      = (int*)alloc((size_t)nbuck * CAPB * 4);
  uint4*    wfrag    = (uint4*)alloc((size_t)3 * 2048 * 16);
  int*      ci       = (int*)alloc((size_t)G * 4);
  int*      flag     = (int*)alloc((size_t)(n + 64) * 4);  // flag[n] = active counter
  int*      list     = (int*)alloc((size_t)n * 4);
  int*      order    = (int*)alloc((size_t)n * 4);
  int*      dhist    = (int*)alloc(64 * 4);
  int*      dcur     = (int*)alloc(64 * 4);
  unsigned* bpool    = (unsigned*)alloc((size_t)nbuck * NBLKA * CAP * 4);
  int*      counts   = (int*)alloc((size_t)nbuck * NBLKA * 4);

  int ciBlocks = (n + 255) / 256;
  int g2 = 2 * G;
  int nob = (n + 255) / 256;
  int actBlocks = (g2 + 255) / 256;
  int* nactive = flag + n;

  k_phase0<<<NBLKA + 24 + ciBlocks, 256, 0, stream>>>(
      esrc, edst, E, nbuck, bpool, counts, conv_w, wfrag, batch, ci, flag, dhist, dcur, n);
  k_build<<<nbuck + t0Blocks, 256, 0, stream>>>(bpool, counts, n, nbuck, maxz, z,
                                                (const float4*)emb, wfrag, dinv, d2, t0,
                                                rowstart, rowend, col, dhist);
  k_order<<<nob + actBlocks, 256, 0, stream>>>(rowstart, rowend, col, dhist, dcur, order,
                                               ci, g2, flag, list, n, nob);
  // layer0: degree-ordered T0/D2 agg + gemm(W1) -> bufA (H'1)
  k_agg0_gemm<<<(n + 15) / 16, 256, 0, stream>>>((const uint4*)t0, d2, rowstart, rowend, col,
                                                 dinv, conv_b, wfrag + 2048, order,
                                                 (uint2*)bufA, n);
  // layer1 agg (active) + gemm(W2): bufA -> bufB (H'2, active rows)
  k_agg_gemmL<<<512, 256, 0, stream>>>((const uint4*)bufA, rowstart, rowend, col, dinv,
                                       conv_b + HD, wfrag + 4096, (uint2*)bufB, list, nactive);
  // layer2 final agg over center rows + head
  k_tail<<<G, 128, 0, stream>>>((const uint4*)bufB, rowstart, rowend, col, dinv,
                                conv_b + 2 * HD, ci, w1, b1, w2, b2, (float*)d_out, G);
}

// Round 23
// 198.249 us; speedup vs baseline: 1.0568x; 1.0568x over previous
//
#include <hip/hip_runtime.h>
#include <hip/hip_fp16.h>

#define HD 128
#define BSH 9              // 512 dst-nodes per bucket
#define NBLKA 256          // phase-A persistent blocks
#define CAP 96             // per (block,bucket) cell capacity (mean ~32, +11 sigma)
#define EDSCAP 10240       // LDS edge stage per bucket (mean ~8.2K)
#define CAPB 12288         // fixed col-region capacity per bucket
// xs tile: 16 rows x 128 halfs, 16B-unit XOR swizzle (col8 ^ row&7)
#define XSW(row, c8) (((size_t)(row) << 7) + ((size_t)(((c8) ^ ((row) & 7))) << 3))

typedef _Float16 half8_t __attribute__((ext_vector_type(8)));
typedef float floatx4 __attribute__((ext_vector_type(4)));

__device__ inline unsigned pack_h2(float x, float y) {
  __half2 h = __floats2half2_rn(x, y);
  return __builtin_bit_cast(unsigned, h);
}
__device__ inline float2 up_h2(unsigned u) {
  __half2 h = __builtin_bit_cast(__half2, u);
  return __half22float2(h);
}

__device__ inline void add8(float* acc, uint4 r) {
  float2 f;
  f = up_h2(r.x); acc[0] += f.x; acc[1] += f.y;
  f = up_h2(r.y); acc[2] += f.x; acc[3] += f.y;
  f = up_h2(r.z); acc[4] += f.x; acc[5] += f.y;
  f = up_h2(r.w); acc[6] += f.x; acc[7] += f.y;
}

__device__ inline void fma8w(float* acc, uint4 r, float w) {
  float2 f;
  f = up_h2(r.x); acc[0] = fmaf(w, f.x, acc[0]); acc[1] = fmaf(w, f.y, acc[1]);
  f = up_h2(r.y); acc[2] = fmaf(w, f.x, acc[2]); acc[3] = fmaf(w, f.y, acc[3]);
  f = up_h2(r.z); acc[4] = fmaf(w, f.x, acc[4]); acc[5] = fmaf(w, f.y, acc[5]);
  f = up_h2(r.w); acc[6] = fmaf(w, f.x, acc[6]); acc[7] = fmaf(w, f.y, acc[7]);
}

// ---- phase 0 (merged): bucketA | W frag pre-pack | ci + flag zero ----
__global__ __launch_bounds__(256) void k_phase0(const int* __restrict__ src,
                                                const int* __restrict__ dst, int E, int nbuck,
                                                unsigned* __restrict__ bpool,
                                                int* __restrict__ counts,
                                                const float* __restrict__ conv_w,
                                                uint4* __restrict__ wfrag,
                                                const int* __restrict__ batch,
                                                int* __restrict__ ci,
                                                int* __restrict__ flag,
                                                int n) {
  __shared__ int cnt[512];
  int b = blockIdx.x;
  if (b < NBLKA) {  // ---- bucketA ----
    for (int i = threadIdx.x; i < nbuck; i += 256) cnt[i] = 0;
    __syncthreads();
    int chunk = (E + NBLKA - 1) / NBLKA;
    int lo = b * chunk, hi = min(E, lo + chunk);
    for (int i = lo + threadIdx.x; i < hi; i += 256) {
      int s = src[i], d = dst[i];
      int bk = d >> BSH;
      int c = atomicAdd(&cnt[bk], 1);
      if (c < CAP)
        bpool[((size_t)bk * NBLKA + b) * CAP + c] =
            ((unsigned)(d & ((1 << BSH) - 1)) << 23) | (unsigned)s;
    }
    __syncthreads();
    for (int bk = threadIdx.x; bk < nbuck; bk += 256) counts[(size_t)bk * NBLKA + b] = cnt[bk];
  } else if (b < NBLKA + 24) {  // ---- wprep ----
    int t = (b - NBLKA) * 256 + threadIdx.x;
    int lane = t & 63;
    int s = (t >> 6) & 3;
    int c4 = (t >> 8) & 3;
    int chalf = (t >> 10) & 1;
    int layer = t >> 11;
    int col = chalf * 64 + c4 * 16 + (lane & 15);
    int k0 = s * 32 + (lane >> 4) * 8;
    const float* W = conv_w + (size_t)layer * HD * HD;
    unsigned u[4];
#pragma unroll
    for (int j = 0; j < 4; ++j)
      u[j] = pack_h2(W[(size_t)(k0 + 2 * j) * HD + col], W[(size_t)(k0 + 2 * j + 1) * HD + col]);
    uint4 o; o.x = u[0]; o.y = u[1]; o.z = u[2]; o.w = u[3];
    wfrag[t] = o;
  } else {  // ---- ci + flag zero ----
    int i = (b - NBLKA - 24) * 256 + threadIdx.x;
    if (i >= n) return;
    flag[i] = 0;
    if (i == 0) flag[n] = 0;  // active counter
    if (i == 0 || batch[i] != batch[i - 1]) ci[batch[i]] = i;
  }
}

// ---- gemm phase: 16 swizzled LDS rows x W -> output rows (dinv nullable) ----
__device__ inline void gemm16(const _Float16* xs, const uint4* __restrict__ wfragL,
                              const float* __restrict__ dinv, uint2* __restrict__ Yh,
                              int row0, int nvalid, const int* __restrict__ rowmap,
                              int tid) {
  int lane = tid & 63, w = tid >> 6;
  int chalf = w >> 1, h = lane >> 4;
  half8_t wf[8];
#pragma unroll
  for (int cc = 0; cc < 2; ++cc)
#pragma unroll
    for (int s = 0; s < 4; ++s) {
      int c4 = 2 * (w & 1) + cc;
      wf[cc * 4 + s] = __builtin_bit_cast(half8_t,
          wfragL[((chalf * 4 + c4) * 4 + s) * 64 + lane]);
    }
  half8_t bf[4];
#pragma unroll
  for (int s = 0; s < 4; ++s)
    bf[s] = *(const half8_t*)&xs[XSW(lane & 15, s * 4 + h)];
  floatx4 acc[2];
  acc[0] = (floatx4){0.f, 0.f, 0.f, 0.f};
  acc[1] = (floatx4){0.f, 0.f, 0.f, 0.f};
#pragma unroll
  for (int s = 0; s < 4; ++s) {
    acc[0] = __builtin_amdgcn_mfma_f32_16x16x32_f16(wf[s], bf[s], acc[0], 0, 0, 0);
    acc[1] = __builtin_amdgcn_mfma_f32_16x16x32_f16(wf[4 + s], bf[s], acc[1], 0, 0, 0);
  }
  int i = row0 + (lane & 15);
  if (i < nvalid) {
    int orow = rowmap ? rowmap[i] : i;
    float dv = dinv ? dinv[orow] : 1.0f;
#pragma unroll
    for (int cc = 0; cc < 2; ++cc) {
      int c4 = 2 * (w & 1) + cc;
      int colbase = chalf * 64 + c4 * 16 + h * 4;
      uint2 o;
      o.x = pack_h2(acc[cc][0] * dv, acc[cc][1] * dv);
      o.y = pack_h2(acc[cc][2] * dv, acc[cc][3] * dv);
      Yh[(size_t)orow * 32 + (colbase >> 2)] = o;
    }
  }
}

// ---- build: CSR per bucket (+D2 table) | T0 = emb_table @ W0 (extra blocks) ----
__global__ __launch_bounds__(256) void k_build(const unsigned* __restrict__ bpool,
                                               const int* __restrict__ counts,
                                               int n, int nbuck, int maxz,
                                               const int* __restrict__ z,
                                               const float4* __restrict__ emb,
                                               const uint4* __restrict__ wfrag0,
                                               float* __restrict__ dinv,
                                               uint2* __restrict__ d2,
                                               uint2* __restrict__ t0,
                                               int* __restrict__ rowstart,
                                               int* __restrict__ rowend,
                                               int* __restrict__ col) {
  __shared__ __align__(16) unsigned eds[EDSCAP];
  __shared__ int hist[1 << BSH];
  __shared__ int wsum[256];
  __shared__ int coff[NBLKA + 1];
  int b = blockIdx.x;
  int t = threadIdx.x;
  if (b >= nbuck) {  // ---- T0 block: rows [rb*16, rb*16+16) of emb_table @ W0 ----
    int rb = b - nbuck;
    _Float16* xs = (_Float16*)eds;
    int grp = t >> 4, li = t & 15;
    int row = rb * 16 + grp;
    int r = row < maxz ? row : maxz - 1;
    const float4* er = emb + (size_t)r * 32 + li * 2;
    float4 f0 = er[0], f1 = er[1];
    uint4 hx;
    hx.x = pack_h2(f0.x, f0.y); hx.y = pack_h2(f0.z, f0.w);
    hx.z = pack_h2(f1.x, f1.y); hx.w = pack_h2(f1.z, f1.w);
    *(uint4*)&xs[XSW(grp, li)] = hx;
    __syncthreads();
    gemm16(xs, wfrag0, nullptr, t0, rb * 16, maxz, nullptr, t);
    return;
  }
  int v = (t < NBLKA) ? min(counts[(size_t)b * NBLKA + t], CAP) : 0;
  wsum[t] = v;
  __syncthreads();
  for (int off = 1; off < NBLKA; off <<= 1) {
    int x = (t >= off) ? wsum[t - off] : 0;
    __syncthreads();
    wsum[t] += x;
    __syncthreads();
  }
  if (t < NBLKA) coff[t] = wsum[t] - v;
  if (t == NBLKA - 1) coff[NBLKA] = wsum[NBLKA - 1];
  __syncthreads();
  int total = min(coff[NBLKA], EDSCAP);
  int w = t >> 6, lane = t & 63;
  for (int blk = w; blk < NBLKA; blk += 4) {
    int off0 = coff[blk], len = coff[blk + 1] - off0;
    const unsigned* seg = bpool + ((size_t)b * NBLKA + blk) * CAP;
    for (int i = lane; i < len; i += 64)
      if (off0 + i < EDSCAP) eds[off0 + i] = seg[i];
  }
  for (int i = t; i < (1 << BSH); i += 256) hist[i] = 0;
  __syncthreads();
  for (int i = t; i < total; i += 256) atomicAdd(&hist[eds[i] >> 23], 1);
  __syncthreads();
  int base = b << BSH;
  int nn = min(1 << BSH, n - base);
  int a0 = hist[2 * t], a1 = hist[2 * t + 1];
  int s = a0 + a1;
  wsum[t] = s;
  __syncthreads();
  for (int off = 1; off < 256; off <<= 1) {
    int x = (t >= off) ? wsum[t - off] : 0;
    __syncthreads();
    wsum[t] += x;
    __syncthreads();
  }
  int excl = wsum[t] - s;
  int cbase = b * CAPB;
  if (2 * t < nn) {
    int i = base + 2 * t;
    float d = 1.0f / sqrtf((float)(a0 + 1));
    rowstart[i] = cbase + excl;
    rowend[i] = cbase + excl + a0;
    dinv[i] = d;
    d2[i] = make_uint2((unsigned)z[i] * 16, __float_as_uint(d));
  }
  if (2 * t + 1 < nn) {
    int i = base + 2 * t + 1;
    float d = 1.0f / sqrtf((float)(a1 + 1));
    rowstart[i] = cbase + excl + a0;
    rowend[i] = cbase + excl + s;
    dinv[i] = d;
    d2[i] = make_uint2((unsigned)z[i] * 16, __float_as_uint(d));
  }
  hist[2 * t] = cbase + excl;
  hist[2 * t + 1] = cbase + excl + a0;
  __syncthreads();
  for (int i = t; i < total; i += 256) {
    unsigned pk = eds[i];
    int dl = pk >> 23;
    int pos = atomicAdd(&hist[dl], 1);
    col[pos] = (int)(pk & 0x7FFFFF);
  }
}

// ---- active set: union of center rows' cols + selves; wave-aggregated append ----
__global__ __launch_bounds__(64) void k_active(const int* __restrict__ ci,
                                               const int* __restrict__ rowstart,
                                               const int* __restrict__ rowend,
                                               const int* __restrict__ col,
                                               int g2, int* __restrict__ flag,
                                               int* __restrict__ list, int n) {
  int lane = threadIdx.x;
  int vid = blockIdx.x * 64 + lane;
  bool haveRow = vid < g2;
  int* nactive = flag + n;
  int node = 0, e = 0, end = 0;
  if (haveRow) {
    node = ci[vid >> 1] + (vid & 1);
    e = rowstart[node];
    end = rowend[node];
  }
  bool neu = haveRow && (atomicExch(&flag[node], 1) == 0);
  unsigned long long m = __ballot(neu);
  int base = 0;
  if (lane == 0 && m) base = atomicAdd(nactive, __popcll(m));
  base = __shfl(base, 0);
  if (neu) list[base + __popcll(m & ((1ULL << lane) - 1))] = node;
  for (;;) {
    bool act = haveRow && (e < end);
    if (!__any(act)) break;
    int s = act ? col[e] : 0;
    bool nw = act && (atomicExch(&flag[s], 1) == 0);
    unsigned long long mm = __ballot(nw);
    int b2 = 0;
    if (lane == 0 && mm) b2 = atomicAdd(nactive, __popcll(mm));
    b2 = __shfl(b2, 0);
    if (nw) list[b2 + __popcll(mm & ((1ULL << lane) - 1))] = s;
    ++e;
  }
}

// ---- layer0 fused: aggregate via T0/D2 (4-wide, D2 prefetched 1 batch ahead) + gemm(W1) ----
__global__ __launch_bounds__(256) void k_agg0_gemm(const uint4* __restrict__ T0,
                                                   const uint2* __restrict__ D2,
                                                   const int* __restrict__ rowstart,
                                                   const int* __restrict__ rowend,
                                                   const int* __restrict__ col,
                                                   const float* __restrict__ dinv,
                                                   const float* __restrict__ bias,
                                                   const uint4* __restrict__ wfragL,
                                                   uint2* __restrict__ Yh, int n) {
  __shared__ __align__(16) _Float16 xs[16 * HD];
  int tid = threadIdx.x;
  int grp = tid >> 4, li = tid & 15;
  int node = blockIdx.x * 16 + grp;
  int nd = node < n ? node : n - 1;
  float acc[8] = {0.f, 0.f, 0.f, 0.f, 0.f, 0.f, 0.f, 0.f};
  uint2 ds = D2[nd];
  fma8w(acc, T0[ds.x + li], __uint_as_float(ds.y));  // self term
  int e0 = rowstart[nd], end = rowend[nd];
  int nb = (end - e0 + 3) >> 2;
  if (nb > 0) {
    uint2 d0, d1, d2v, d3;
    // load batch 0 (mask-padded; 0u bits == +0.0f weight)
    {
      int c0 = col[e0], c1 = col[min(e0 + 1, end - 1)];
      int c2 = col[min(e0 + 2, end - 1)], c3 = col[min(e0 + 3, end - 1)];
      d0 = D2[c0]; d1 = D2[c1]; d2v = D2[c2]; d3 = D2[c3];
      if (e0 + 1 >= end) d1.y = 0u;
      if (e0 + 2 >= end) d2v.y = 0u;
      if (e0 + 3 >= end) d3.y = 0u;
    }
    for (int it = 1; it < nb; ++it) {
      int e = e0 + it * 4;
      // prefetch next D2 batch (independent of current T0 consumption)
      int c0 = col[e], c1 = col[min(e + 1, end - 1)];
      int c2 = col[min(e + 2, end - 1)], c3 = col[min(e + 3, end - 1)];
      uint2 n0 = D2[c0], n1 = D2[c1], n2 = D2[c2], n3 = D2[c3];
      if (e + 1 >= end) n1.y = 0u;
      if (e + 2 >= end) n2.y = 0u;
      if (e + 3 >= end) n3.y = 0u;
      // consume current batch
      fma8w(acc, T0[d0.x + li], __uint_as_float(d0.y));
      fma8w(acc, T0[d1.x + li], __uint_as_float(d1.y));
      fma8w(acc, T0[d2v.x + li], __uint_as_float(d2v.y));
      fma8w(acc, T0[d3.x + li], __uint_as_float(d3.y));
      d0 = n0; d1 = n1; d2v = n2; d3 = n3;
    }
    fma8w(acc, T0[d0.x + li], __uint_as_float(d0.y));
    fma8w(acc, T0[d1.x + li], __uint_as_float(d1.y));
    fma8w(acc, T0[d2v.x + li], __uint_as_float(d2v.y));
    fma8w(acc, T0[d3.x + li], __uint_as_float(d3.y));
  }
  float dv = dinv[nd];
  float4 b0 = ((const float4*)bias)[2 * li];
  float4 b1 = ((const float4*)bias)[2 * li + 1];
  acc[0] = fmaxf(fmaf(dv, acc[0], b0.x), 0.f);
  acc[1] = fmaxf(fmaf(dv, acc[1], b0.y), 0.f);
  acc[2] = fmaxf(fmaf(dv, acc[2], b0.z), 0.f);
  acc[3] = fmaxf(fmaf(dv, acc[3], b0.w), 0.f);
  acc[4] = fmaxf(fmaf(dv, acc[4], b1.x), 0.f);
  acc[5] = fmaxf(fmaf(dv, acc[5], b1.y), 0.f);
  acc[6] = fmaxf(fmaf(dv, acc[6], b1.z), 0.f);
  acc[7] = fmaxf(fmaf(dv, acc[7], b1.w), 0.f);
  uint4 hx;
  hx.x = pack_h2(acc[0], acc[1]); hx.y = pack_h2(acc[2], acc[3]);
  hx.z = pack_h2(acc[4], acc[5]); hx.w = pack_h2(acc[6], acc[7]);
  *(uint4*)&xs[XSW(grp, li)] = hx;
  __syncthreads();
  gemm16(xs, wfragL, dinv, Yh, blockIdx.x * 16, n, nullptr, tid);
}

// ---- fused aggregate + gemm over the active list (grid-stride tiles of 16) ----
__global__ __launch_bounds__(256) void k_agg_gemmL(const uint4* __restrict__ H,
                                                   const int* __restrict__ rowstart,
                                                   const int* __restrict__ rowend,
                                                   const int* __restrict__ col,
                                                   const float* __restrict__ dinv,
                                                   const float* __restrict__ bias,
                                                   const uint4* __restrict__ wfragL,
                                                   uint2* __restrict__ Yh,
                                                   const int* __restrict__ list,
                                                   const int* __restrict__ nactive) {
  __shared__ __align__(16) _Float16 xs[16 * HD];
  int na = *nactive;
  int tid = threadIdx.x;
  int grp = tid >> 4, li = tid & 15;
  for (int tile = blockIdx.x; tile * 16 < na; tile += gridDim.x) {
    int i = tile * 16 + grp;
    int node = list[i < na ? i : na - 1];
    uint4 srow = H[(size_t)node * 16 + li];
    float acc[8] = {0.f, 0.f, 0.f, 0.f, 0.f, 0.f, 0.f, 0.f};
    add8(acc, srow);
    int e = rowstart[node], end = rowend[node];
    for (; e + 3 < end; e += 4) {
      int c0 = col[e], c1 = col[e + 1], c2 = col[e + 2], c3 = col[e + 3];
      uint4 r0 = H[(size_t)c0 * 16 + li];
      uint4 r1 = H[(size_t)c1 * 16 + li];
      uint4 r2 = H[(size_t)c2 * 16 + li];
      uint4 r3 = H[(size_t)c3 * 16 + li];
      add8(acc, r0);
      add8(acc, r1);
      add8(acc, r2);
      add8(acc, r3);
    }
    for (; e < end; ++e) {
      uint4 r = H[(size_t)col[e] * 16 + li];
      add8(acc, r);
    }
    float dv = dinv[node];
    float4 b0 = ((const float4*)bias)[2 * li];
    float4 b1 = ((const float4*)bias)[2 * li + 1];
    acc[0] = fmaxf(fmaf(dv, acc[0], b0.x), 0.f);
    acc[1] = fmaxf(fmaf(dv, acc[1], b0.y), 0.f);
    acc[2] = fmaxf(fmaf(dv, acc[2], b0.z), 0.f);
    acc[3] = fmaxf(fmaf(dv, acc[3], b0.w), 0.f);
    acc[4] = fmaxf(fmaf(dv, acc[4], b1.x), 0.f);
    acc[5] = fmaxf(fmaf(dv, acc[5], b1.y), 0.f);
    acc[6] = fmaxf(fmaf(dv, acc[6], b1.z), 0.f);
    acc[7] = fmaxf(fmaf(dv, acc[7], b1.w), 0.f);
    uint4 hx;
    hx.x = pack_h2(acc[0], acc[1]); hx.y = pack_h2(acc[2], acc[3]);
    hx.z = pack_h2(acc[4], acc[5]); hx.w = pack_h2(acc[6], acc[7]);
    *(uint4*)&xs[XSW(grp, li)] = hx;
    __syncthreads();
    gemm16(xs, wfragL, dinv, Yh, tile * 16, na, list, tid);
    __syncthreads();
  }
}

// ---- fused tail: final aggregate of both center rows + product + MLP head ----
__global__ __launch_bounds__(128) void k_tail(const uint4* __restrict__ H,
                                              const int* __restrict__ rowstart,
                                              const int* __restrict__ rowend,
                                              const int* __restrict__ col,
                                              const float* __restrict__ dinv,
                                              const float* __restrict__ bias,
                                              const int* __restrict__ ci,
                                              const float* __restrict__ W1,
                                              const float* __restrict__ b1,
                                              const float* __restrict__ w2,
                                              const float* __restrict__ b2,
                                              float* __restrict__ out, int G) {
  __shared__ float part[8][HD];
  __shared__ float xs[HD];
  __shared__ float red[HD];
  int g = blockIdx.x;
  int t = threadIdx.x;
  int grp = t >> 4, li = t & 15;
  int nodeA = ci[g];
  int node = nodeA + (grp >> 2);   // 0-3 -> A, 4-7 -> B
  int gi = grp & 3;
  float acc[8] = {0.f, 0.f, 0.f, 0.f, 0.f, 0.f, 0.f, 0.f};
  if (gi == 0) add8(acc, H[(size_t)node * 16 + li]);  // self term
  for (int e = rowstart[node] + gi; e < rowend[node]; e += 4) {
    uint4 r = H[(size_t)col[e] * 16 + li];
    add8(acc, r);
  }
#pragma unroll
  for (int j = 0; j < 8; ++j) part[grp][li * 8 + j] = acc[j];
  __syncthreads();
  float sumA = part[0][t] + part[1][t] + part[2][t] + part[3][t];
  float sumB = part[4][t] + part[5][t] + part[6][t] + part[7][t];
  float bb = bias[t];
  float va = fmaf(dinv[nodeA], sumA, bb);
  float vb = fmaf(dinv[nodeA + 1], sumB, bb);
  xs[t] = va * vb;
  __syncthreads();
  float hacc = b1[t];
#pragma unroll 8
  for (int k = 0; k < HD; ++k) hacc = fmaf(xs[k], W1[k * HD + t], hacc);
  hacc = fmaxf(hacc, 0.f);
  red[t] = hacc * w2[t];
  __syncthreads();
  for (int off = 64; off > 0; off >>= 1) {
    if (t < off) red[t] += red[t + off];
    __syncthreads();
  }
  if (t == 0) out[g] = red[0] + b2[0];
}

extern "C" void kernel_launch(void* const* d_in, const int* in_sizes, int n_in,
                              void* d_out, int out_size, void* d_ws, size_t ws_size,
                              hipStream_t stream) {
  (void)n_in; (void)ws_size;
  const int*   z      = (const int*)d_in[1];
  const int*   ei     = (const int*)d_in[2];
  const int*   batch  = (const int*)d_in[3];
  const float* emb    = (const float*)d_in[4];
  const float* conv_w = (const float*)d_in[5];
  const float* conv_b = (const float*)d_in[6];
  const float* w1     = (const float*)d_in[7];
  const float* b1     = (const float*)d_in[8];
  const float* w2     = (const float*)d_in[9];
  const float* b2     = (const float*)d_in[10];
  int n = in_sizes[1];
  int E = in_sizes[2] / 2;
  int G = out_size;
  int maxz = in_sizes[4] / HD;
  const int* esrc = ei;
  const int* edst = ei + E;
  int nbuck = (n + (1 << BSH) - 1) >> BSH;
  int t0Blocks = (maxz + 15) / 16;

  char* p = (char*)d_ws;
  auto alloc = [&](size_t bytes) { void* r = (void*)p; p += (bytes + 255) / 256 * 256; return r; };
  unsigned* bufA     = (unsigned*)alloc((size_t)n * HD * 2);  // half, row-major
  unsigned* bufB     = (unsigned*)alloc((size_t)n * HD * 2);  // half, row-major
  float*    dinv     = (float*)alloc((size_t)n * 4);
  uint2*    d2       = (uint2*)alloc((size_t)n * 8);
  uint2*    t0       = (uint2*)alloc((size_t)(t0Blocks * 16) * 32 * 8);  // fp16 rows
  int*      rowstart = (int*)alloc((size_t)n * 4);
  int*      rowend   = (int*)alloc((size_t)n * 4);
  int*      col      = (int*)alloc((size_t)nbuck * CAPB * 4);
  uint4*    wfrag    = (uint4*)alloc((size_t)3 * 2048 * 16);
  int*      ci       = (int*)alloc((size_t)G * 4);
  int*      flag     = (int*)alloc((size_t)(n + 64) * 4);  // flag[n] = active counter
  int*      list     = (int*)alloc((size_t)n * 4);
  unsigned* bpool    = (unsigned*)alloc((size_t)nbuck * NBLKA * CAP * 4);
  int*      counts   = (int*)alloc((size_t)nbuck * NBLKA * 4);

  int ciBlocks = (n + 255) / 256;
  int g2 = 2 * G;
  int* nactive = flag + n;

  k_phase0<<<NBLKA + 24 + ciBlocks, 256, 0, stream>>>(
      esrc, edst, E, nbuck, bpool, counts, conv_w, wfrag, batch, ci, flag, n);
  k_build<<<nbuck + t0Blocks, 256, 0, stream>>>(bpool, counts, n, nbuck, maxz, z,
                                                (const float4*)emb, wfrag, dinv, d2, t0,
                                                rowstart, rowend, col);
  k_active<<<(g2 + 63) / 64, 64, 0, stream>>>(ci, rowstart, rowend, col, g2, flag, list, n);
  // layer0: T0/D2-based agg + gemm(W1) -> bufA (H'1)
  k_agg0_gemm<<<(n + 15) / 16, 256, 0, stream>>>((const uint4*)t0, d2, rowstart, rowend, col,
                                                 dinv, conv_b, wfrag + 2048, (uint2*)bufA, n);
  // layer1 agg (active) + gemm(W2): bufA -> bufB (H'2, active rows)
  k_agg_gemmL<<<512, 256, 0, stream>>>((const uint4*)bufA, rowstart, rowend, col, dinv,
                                       conv_b + HD, wfrag + 4096, (uint2*)bufB, list, nactive);
  // layer2 final agg over center rows + head
  k_tail<<<G, 128, 0, stream>>>((const uint4*)bufB, rowstart, rowend, col, dinv,
                                conv_b + 2 * HD, ci, w1, b1, w2, b2, (float*)d_out, G);
}